// Round 1
// baseline (887.467 us; speedup 1.0000x reference)
//
#include <hip/hip_runtime.h>
#include <math.h>

#define DD 128
#define COUT 40
#define BN_EPS 1e-5f
#define L2_EPS 1e-12f

// ---------------- setup kernels ----------------

__global__ void k_init(int* deg, int* fill, int n) {
    int i = blockIdx.x * blockDim.x + threadIdx.x;
    if (i < n) { deg[i] = 1; fill[i] = 0; }   // deg starts at 1 (self loop)
}

__global__ void k_hist(const int* ei, int E, int* deg) {
    int i = blockIdx.x * blockDim.x + threadIdx.x;
    if (i < E) atomicAdd(&deg[ei[E + i]], 1);   // dst = ei[E+i]
}

__global__ void k_dinv(const int* deg, float* dinv, int n) {
    int i = blockIdx.x * blockDim.x + threadIdx.x;
    if (i < n) dinv[i] = rsqrtf((float)deg[i]);
}

// exclusive scan over n+1 entries (deg[i] for i<n, 0 for i==n), 3 phases
__global__ void k_scan_a(const int* deg, int* row_ptr, int* bsum, int n) {
    __shared__ int s[256];
    int t = threadIdx.x;
    int idx = blockIdx.x * 256 + t;
    int v = (idx < n) ? deg[idx] : 0;
    s[t] = v; __syncthreads();
    for (int off = 1; off < 256; off <<= 1) {
        int x = (t >= off) ? s[t - off] : 0;
        __syncthreads(); s[t] += x; __syncthreads();
    }
    if (idx <= n) row_ptr[idx] = s[t] - v;     // local exclusive
    if (t == 255) bsum[blockIdx.x] = s[255];
}

__global__ void k_scan_b(const int* bsum, int* boff, int nb) {
    __shared__ int s[512];
    int t = threadIdx.x;
    int v = (t < nb) ? bsum[t] : 0;
    s[t] = v; __syncthreads();
    for (int off = 1; off < 512; off <<= 1) {
        int x = (t >= off) ? s[t - off] : 0;
        __syncthreads(); s[t] += x; __syncthreads();
    }
    if (t < nb) boff[t] = s[t] - v;            // exclusive block offsets
}

__global__ void k_scan_c(int* row_ptr, const int* boff, int n1) {
    int idx = blockIdx.x * blockDim.x + threadIdx.x;
    if (idx < n1) row_ptr[idx] += boff[idx >> 8];
}

__global__ void k_fill(const int* ei, int E, int n, const int* row_ptr,
                       int* fill, int* colidx) {
    int i = blockIdx.x * blockDim.x + threadIdx.x;
    int total = E + n;
    if (i >= total) return;
    int u, v;
    if (i < E) { u = ei[i]; v = ei[E + i]; }
    else { u = i - E; v = u; }                 // self loop
    int p = atomicAdd(&fill[v], 1);
    colidx[row_ptr[v] + p] = u;
}

// ---------------- compute kernels ----------------

// C[:, half*64 : half*64+64] = A @ W[:, half*64 : ...]; W is 128x128 row-major
__global__ __launch_bounds__(256) void k_gemm(const float* __restrict__ A,
                                              const float* __restrict__ W,
                                              float* __restrict__ C, int nrows) {
    __shared__ float Wl[128 * 64];
    int half = blockIdx.y;
    for (int i = threadIdx.x; i < 128 * 16; i += 256) {
        int k = i >> 4, c4 = i & 15;
        *(float4*)&Wl[k * 64 + c4 * 4] =
            *(const float4*)&W[k * 128 + half * 64 + c4 * 4];
    }
    __syncthreads();
    int row = blockIdx.x * 256 + threadIdx.x;
    if (row >= nrows) return;
    const float* Ar = A + (size_t)row * DD;
    float acc[64];
#pragma unroll
    for (int c = 0; c < 64; c++) acc[c] = 0.f;
    for (int k0 = 0; k0 < 128; k0 += 4) {
        float4 a = *(const float4*)(Ar + k0);
        float av[4] = {a.x, a.y, a.z, a.w};
#pragma unroll
        for (int kk = 0; kk < 4; kk++) {
            const float* wr = &Wl[(k0 + kk) * 64];
#pragma unroll
            for (int c = 0; c < 64; c++) acc[c] += av[kk] * wr[c];
        }
    }
    float* Cr = C + (size_t)row * DD + half * 64;
#pragma unroll
    for (int c4 = 0; c4 < 16; c4++)
        *(float4*)&Cr[c4 * 4] =
            make_float4(acc[c4 * 4], acc[c4 * 4 + 1], acc[c4 * 4 + 2], acc[c4 * 4 + 3]);
}

// out[v] = bias + sum_{j} dinv[v]*dinv[col[j]] * lin[col[j]]   (one wave per node)
__global__ void k_agg(const float* __restrict__ lin, const int* __restrict__ row_ptr,
                      const int* __restrict__ colidx, const float* __restrict__ dinv,
                      const float* __restrict__ bias, float* __restrict__ out, int n) {
    int v = blockIdx.x * blockDim.y + threadIdx.y;
    if (v >= n) return;
    int lane = threadIdx.x;
    int c = lane * 2;
    int s = row_ptr[v], e = row_ptr[v + 1];
    float dv = dinv[v];
    float ax = bias[c], ay = bias[c + 1];
    for (int j = s; j < e; ++j) {
        int u = colidx[j];
        float w = dv * dinv[u];
        float2 t = *(const float2*)&lin[(size_t)u * DD + c];
        ax += w * t.x; ay += w * t.y;
    }
    *(float2*)&out[(size_t)v * DD + c] = make_float2(ax, ay);
}

__global__ void k_zero(float* p, int n) {
    int i = blockIdx.x * blockDim.x + threadIdx.x;
    if (i < n) p[i] = 0.f;
}

// stats[0..127] = col sums, stats[128..255] = col sums of squares
__global__ __launch_bounds__(256) void k_bnstats(const float* __restrict__ X, int n,
                                                 float* __restrict__ stats) {
    int cg = (threadIdx.x & 31) * 4;      // column quad
    int rg = threadIdx.x >> 5;            // row group 0..7
    float s0 = 0, s1 = 0, s2 = 0, s3 = 0;
    float q0 = 0, q1 = 0, q2 = 0, q3 = 0;
    for (int r = blockIdx.x * 8 + rg; r < n; r += gridDim.x * 8) {
        float4 x = *(const float4*)&X[(size_t)r * DD + cg];
        s0 += x.x; s1 += x.y; s2 += x.z; s3 += x.w;
        q0 += x.x * x.x; q1 += x.y * x.y; q2 += x.z * x.z; q3 += x.w * x.w;
    }
    __shared__ float sh[8][128];
    __shared__ float qh[8][128];
    sh[rg][cg] = s0; sh[rg][cg + 1] = s1; sh[rg][cg + 2] = s2; sh[rg][cg + 3] = s3;
    qh[rg][cg] = q0; qh[rg][cg + 1] = q1; qh[rg][cg + 2] = q2; qh[rg][cg + 3] = q3;
    __syncthreads();
    if (threadIdx.x < 128) {
        float a = 0, b = 0;
        for (int g = 0; g < 8; g++) { a += sh[g][threadIdx.x]; b += qh[g][threadIdx.x]; }
        atomicAdd(&stats[threadIdx.x], a);
        atomicAdd(&stats[128 + threadIdx.x], b);
    }
}

// ss[0..127]=scale, ss[128..255]=shift
__global__ void k_bnfinal(const float* stats, const float* g, const float* be,
                          float* ss, float inv_n) {
    int c = threadIdx.x;
    float mu = stats[c] * inv_n;
    float var = stats[128 + c] * inv_n - mu * mu;
    float sc = g[c] * rsqrtf(var + BN_EPS);
    ss[c] = sc;
    ss[128 + c] = be[c] - mu * sc;
}

// y = relu(x*scale+shift) (+res); row L2 normalize. One wave per node.
__global__ void k_post(const float* __restrict__ X, const float* __restrict__ ss,
                       const float* __restrict__ res, float* __restrict__ out, int n) {
    int v = blockIdx.x * blockDim.y + threadIdx.y;
    if (v >= n) return;
    int lane = threadIdx.x;
    int c = lane * 2;
    float2 x = *(const float2*)&X[(size_t)v * DD + c];
    float y0 = fmaxf(x.x * ss[c] + ss[128 + c], 0.f);
    float y1 = fmaxf(x.y * ss[c + 1] + ss[128 + c + 1], 0.f);
    if (res) {
        float2 r = *(const float2*)&res[(size_t)v * DD + c];
        y0 += r.x; y1 += r.y;
    }
    float sum = y0 * y0 + y1 * y1;
    for (int m = 1; m < 64; m <<= 1) sum += __shfl_xor(sum, m, 64);
    float inv = 1.f / fmaxf(sqrtf(sum), L2_EPS);
    *(float2*)&out[(size_t)v * DD + c] = make_float2(y0 * inv, y1 * inv);
}

// logits = h @ Wout + bout;  Wout: 128x40
__global__ __launch_bounds__(256) void k_outgemm(const float* __restrict__ A,
                                                 const float* __restrict__ W,
                                                 const float* __restrict__ b,
                                                 float* __restrict__ C, int n) {
    __shared__ float Wl[128 * COUT];
    for (int i = threadIdx.x; i < 128 * COUT; i += 256) Wl[i] = W[i];
    __syncthreads();
    int row = blockIdx.x * 256 + threadIdx.x;
    if (row >= n) return;
    const float* Ar = A + (size_t)row * DD;
    float acc[COUT];
#pragma unroll
    for (int c = 0; c < COUT; c++) acc[c] = b[c];
    for (int k0 = 0; k0 < 128; k0 += 4) {
        float4 a = *(const float4*)(Ar + k0);
        float av[4] = {a.x, a.y, a.z, a.w};
#pragma unroll
        for (int kk = 0; kk < 4; kk++) {
            const float* wr = &Wl[(k0 + kk) * COUT];
#pragma unroll
            for (int c = 0; c < COUT; c++) acc[c] += av[kk] * wr[c];
        }
    }
    float* Cr = C + (size_t)row * COUT;
#pragma unroll
    for (int c4 = 0; c4 < COUT / 4; c4++)
        *(float4*)&Cr[c4 * 4] =
            make_float4(acc[c4 * 4], acc[c4 * 4 + 1], acc[c4 * 4 + 2], acc[c4 * 4 + 3]);
}

// ---------------- host ----------------

extern "C" void kernel_launch(void* const* d_in, const int* in_sizes, int n_in,
                              void* d_out, int out_size, void* d_ws, size_t ws_size,
                              hipStream_t stream) {
    const float* x    = (const float*)d_in[0];
    const int*   ei   = (const int*)d_in[1];
    const float* W1   = (const float*)d_in[2];
    const float* b1   = (const float*)d_in[3];
    const float* W2   = (const float*)d_in[4];
    const float* b2   = (const float*)d_in[5];
    const float* W3   = (const float*)d_in[6];
    const float* b3   = (const float*)d_in[7];
    const float* g1   = (const float*)d_in[8];
    const float* be1  = (const float*)d_in[9];
    const float* g2   = (const float*)d_in[10];
    const float* be2  = (const float*)d_in[11];
    const float* g3   = (const float*)d_in[12];
    const float* be3  = (const float*)d_in[13];
    const float* Wout = (const float*)d_in[14];
    const float* bout = (const float*)d_in[15];
    float* out = (float*)d_out;

    const int N = in_sizes[0] / DD;
    const int E = in_sizes[1] / 2;
    const int NNZ = E + N;

    // workspace layout
    char* w = (char*)d_ws;
    float* bufA = (float*)w;                 w += (size_t)N * DD * sizeof(float);
    float* bufB = (float*)w;                 w += (size_t)N * DD * sizeof(float);
    float* bufC = (float*)w;                 w += (size_t)N * DD * sizeof(float);
    int* deg     = (int*)w;                  w += (size_t)N * sizeof(int);
    int* fill    = (int*)w;                  w += (size_t)N * sizeof(int);
    int* row_ptr = (int*)w;                  w += (size_t)(N + 1) * sizeof(int);
    int* colidx  = (int*)w;                  w += (size_t)NNZ * sizeof(int);
    float* dinv  = (float*)w;                w += (size_t)N * sizeof(float);
    int* bsum    = (int*)w;                  w += 512 * sizeof(int);
    int* boff    = (int*)w;                  w += 512 * sizeof(int);
    float* stats = (float*)w;                w += 256 * sizeof(float);
    float* ss    = (float*)w;                w += 256 * sizeof(float);

    const int NB = (N + 1 + 255) / 256;      // scan blocks

    // ---- CSR build ----
    k_init<<<(N + 255) / 256, 256, 0, stream>>>(deg, fill, N);
    k_hist<<<(E + 255) / 256, 256, 0, stream>>>(ei, E, deg);
    k_dinv<<<(N + 255) / 256, 256, 0, stream>>>(deg, dinv, N);
    k_scan_a<<<NB, 256, 0, stream>>>(deg, row_ptr, bsum, N);
    k_scan_b<<<1, 512, 0, stream>>>(bsum, boff, NB);
    k_scan_c<<<(N + 1 + 255) / 256, 256, 0, stream>>>(row_ptr, boff, N + 1);
    k_fill<<<(NNZ + 255) / 256, 256, 0, stream>>>(ei, E, N, row_ptr, fill, colidx);

    dim3 gemmGrid((N + 255) / 256, 2);
    dim3 waveGrid((N + 3) / 4);
    dim3 waveBlk(64, 4);
    float inv_n = 1.0f / (float)N;

    // ---- layer 1 ----
    k_gemm<<<gemmGrid, 256, 0, stream>>>(x, W1, bufB, N);
    k_agg<<<waveGrid, waveBlk, 0, stream>>>(bufB, row_ptr, colidx, dinv, b1, bufA, N);
    k_zero<<<1, 256, 0, stream>>>(stats, 256);
    k_bnstats<<<512, 256, 0, stream>>>(bufA, N, stats);
    k_bnfinal<<<1, 128, 0, stream>>>(stats, g1, be1, ss, inv_n);
    k_post<<<waveGrid, waveBlk, 0, stream>>>(bufA, ss, nullptr, bufA, N);   // h1 in bufA

    // ---- layer 2 ----
    k_gemm<<<gemmGrid, 256, 0, stream>>>(bufA, W2, bufB, N);
    k_agg<<<waveGrid, waveBlk, 0, stream>>>(bufB, row_ptr, colidx, dinv, b2, bufC, N);
    k_zero<<<1, 256, 0, stream>>>(stats, 256);
    k_bnstats<<<512, 256, 0, stream>>>(bufC, N, stats);
    k_bnfinal<<<1, 128, 0, stream>>>(stats, g2, be2, ss, inv_n);
    k_post<<<waveGrid, waveBlk, 0, stream>>>(bufC, ss, bufA, bufC, N);      // h2 in bufC

    // ---- layer 3 ----
    k_gemm<<<gemmGrid, 256, 0, stream>>>(bufC, W3, bufB, N);
    k_agg<<<waveGrid, waveBlk, 0, stream>>>(bufB, row_ptr, colidx, dinv, b3, bufA, N);
    k_zero<<<1, 256, 0, stream>>>(stats, 256);
    k_bnstats<<<512, 256, 0, stream>>>(bufA, N, stats);
    k_bnfinal<<<1, 128, 0, stream>>>(stats, g3, be3, ss, inv_n);
    k_post<<<waveGrid, waveBlk, 0, stream>>>(bufA, ss, bufC, bufA, N);      // h3 in bufA

    // ---- output ----
    k_outgemm<<<(N + 255) / 256, 256, 0, stream>>>(bufA, Wout, bout, out, N);
}